// Round 9
// baseline (96.251 us; speedup 1.0000x reference)
//
#include <hip/hip_runtime.h>
#include <math.h>

#define BB 32
#define HH 256
#define WW 256
#define HW (HH*WW)
#define K_BG 0.1f
#define RELAX 5.0f
#define EPS_D 1e-7
#define RPB 8              // rows per k_mega block

typedef unsigned long long u64;
typedef unsigned short u16;

__device__ __forceinline__ float sigf(float x) { return 1.0f / (1.0f + expf(-x)); }

__device__ __forceinline__ u64 shflx64(u64 x, int s) {
    return (u64)__shfl_xor((unsigned long long)x, s, 64);
}

// ---------------- binary 5x5 dilation as bit-ops -> row masks ----------------
// dmaskT: dilated mask, WORD-MAJOR  [b][word w][row]   (k_transp's input layout)
// nzmask: raw target mask, row-major [b][row][word]
__global__ void k_maskdil(const float* __restrict__ tg, u64* __restrict__ dmaskT,
                          u64* __restrict__ nzmask) {
    __shared__ u64 nz[20][4];
    __shared__ u64 hd[20][4];
    int blk = blockIdx.x;              // 32 images x 16 bands of 16 rows
    int b = blk >> 4, band = blk & 15;
    int r0 = band * 16;
    int t = threadIdx.x, w = t >> 6;
    const float* img = tg + b * HW;
    for (int rr = 0; rr < 20; ++rr) {
        int rg = r0 + rr - 2;
        float v = (rg >= 0 && rg < HH) ? img[rg * WW + t] : 0.0f;
        u64 bal = __ballot(v != 0.0f);
        if ((t & 63) == 0) nz[rr][w] = bal;
    }
    __syncthreads();
    if (t < 80) {                      // 20 rows x 4 words: horizontal +-2 dilate
        int rr = t >> 2, k = t & 3;
        u64 m = nz[rr][k];
        u64 ml = (k > 0) ? nz[rr][k - 1] : 0ULL;
        u64 mr = (k < 3) ? nz[rr][k + 1] : 0ULL;
        hd[rr][k] = m | (m << 1) | (m << 2) | (m >> 1) | (m >> 2)
                  | (ml >> 62) | (ml >> 63) | (mr << 62) | (mr << 63);
    }
    if (t < 64) {                      // raw masks for the 16 owned rows
        int rr = t >> 2, k = t & 3;
        nzmask[b * 1024 + (r0 + rr) * 4 + k] = nz[rr + 2][k];
    }
    __syncthreads();
    if (t < 64) {                      // 16 rows x 4 words: vertical +-2 dilate
        int rr = t >> 2, k = t & 3;
        u64 o = hd[rr][k] | hd[rr + 1][k] | hd[rr + 2][k] | hd[rr + 3][k] | hd[rr + 4][k];
        dmaskT[b * 1024 + k * 256 + (r0 + rr)] = o;   // word-major
    }
}

// ---------------- one butterfly bit-transpose per image -> column-major mask --
// cmask[b*1024 + col*4 + g]: bits = rows 64g..64g+63 of column col (dilated mask)
__global__ void k_transp(const u64* __restrict__ dmaskT, u64* __restrict__ cmask) {
    int b = blockIdx.x;
    int tid = threadIdx.x, lane = tid & 63, wv = tid >> 6;
    const u64* base = dmaskT + b * 1024;
    const u64 L32 = 0x00000000FFFFFFFFULL, L16 = 0x0000FFFF0000FFFFULL,
              L8  = 0x00FF00FF00FF00FFULL, L4  = 0x0F0F0F0F0F0F0F0FULL,
              L2  = 0x3333333333333333ULL, L1  = 0x5555555555555555ULL;
    #pragma unroll
    for (int w = 0; w < 4; ++w) {
        u64 x = base[w * 256 + wv * 64 + lane];   // row (64wv+lane), word w
        u64 pp;
        pp = shflx64(x, 32); x = (lane & 32) ? ((x & ~L32) | ((pp & ~L32) >> 32)) : ((x & L32) | ((pp & L32) << 32));
        pp = shflx64(x, 16); x = (lane & 16) ? ((x & ~L16) | ((pp & ~L16) >> 16)) : ((x & L16) | ((pp & L16) << 16));
        pp = shflx64(x,  8); x = (lane &  8) ? ((x & ~L8 ) | ((pp & ~L8 ) >>  8)) : ((x & L8 ) | ((pp & L8 ) <<  8));
        pp = shflx64(x,  4); x = (lane &  4) ? ((x & ~L4 ) | ((pp & ~L4 ) >>  4)) : ((x & L4 ) | ((pp & L4 ) <<  4));
        pp = shflx64(x,  2); x = (lane &  2) ? ((x & ~L2 ) | ((pp & ~L2 ) >>  2)) : ((x & L2 ) | ((pp & L2 ) <<  2));
        pp = shflx64(x,  1); x = (lane &  1) ? ((x & ~L1 ) | ((pp & ~L1 ) >>  1)) : ((x & L1 ) | ((pp & L1 ) <<  1));
        cmask[b * 1024 + (w * 64 + lane) * 4 + wv] = x;   // column-major
    }
}

// ---------------- mega: bit-parallel EDT + dice partials, 8 rows per block ----
// Column mask comes precomputed (cmask): vertical distance = clz/ctz over 4
// words, then the exact early-exit min-plus walk (f32 arithmetic identical to
// the reference separable EDT, incl. the 1e4/1e8 sentinel).
__global__ __launch_bounds__(256) void k_mega(const float* __restrict__ preds,
                                              const u64* __restrict__ cmask,
                                              const u64* __restrict__ nzmask,
                                              float4* __restrict__ part1,
                                              float4* __restrict__ part2) {
    __shared__ u16 gS[RPB][WW];
    __shared__ float red[8][4];
    int blk = blockIdx.x;              // b*32 + q ; rows 8q..8q+7
    int b = blk >> 5, q = blk & 31;
    int i0 = q * RPB;
    int tid = threadIdx.x;
    int lane = tid & 63, wv = tid >> 6;
    int j = tid;                       // this thread's column

    float p[RPB];
    #pragma unroll
    for (int rr = 0; rr < RPB; ++rr)
        p[rr] = preds[(b * HH + i0 + rr) * WW + j];

    u64 yw[4];                         // set bit = zero pixel, column j
    {
        const u64* cm = cmask + b * 1024 + j * 4;
        #pragma unroll
        for (int g = 0; g < 4; ++g) yw[g] = ~cm[g];
    }

    // ---- branchless vertical distance for RPB pixels (same column) ----
    #pragma unroll
    for (int rr = 0; rr < RPB; ++rr) {
        int i = i0 + rr;
        int iw = i >> 6, ib = i & 63;
        u64 lowm  = (2ULL << ib) - 1ULL;          // bits 0..ib (ib=63 -> ~0)
        u64 highm = ~((1ULL << ib) - 1ULL);       // bits ib..63
        int pu = -1, pd = -1;
        #pragma unroll
        for (int w = 0; w < 4; ++w) {             // ascending: highest nonzero word wins
            u64 m = (w < iw) ? ~0ULL : ((w == iw) ? lowm : 0ULL);
            u64 z = yw[w] & m;
            int cand = (w << 6) + 63 - __clzll(z);
            pu = z ? cand : pu;
        }
        #pragma unroll
        for (int w = 3; w >= 0; --w) {            // descending: lowest nonzero word wins
            u64 m = (w > iw) ? ~0ULL : ((w == iw) ? highm : 0ULL);
            u64 z = yw[w] & m;
            int cand = (w << 6) + (__ffsll((unsigned long long)z) - 1);
            pd = z ? cand : pd;
        }
        int up = (pu >= 0) ? (i - pu) : 10000;
        int dn = (pd >= 0) ? (pd - i) : 10000;
        gS[rr][j] = (u16)min(min(up, dn), 10000);
    }
    __syncthreads();

    // ---- min-plus walk + dice partials ----
    float vals[8];
    #pragma unroll
    for (int qq = 0; qq < 6; ++qq) vals[qq] = 0.0f;
    vals[6] = 1e30f; vals[7] = 0.0f;
    #pragma unroll
    for (int rr = 0; rr < RPB; ++rr) {
        int i = i0 + rr;
        float gv = (float)gS[rr][j];
        float best = gv * gv;
        for (int r = 1; r < WW; ++r) {
            float rf = (float)(r * r);
            if (rf >= best) break;
            int jl = j - r, jr = j + r;
            if (jl >= 0) { float v = (float)gS[rr][jl]; best = fminf(best, v * v + rf); }
            if (jr < WW) { float v = (float)gS[rr][jr]; best = fminf(best, v * v + rf); }
        }
        float dv = sqrtf(best);
        float sp = sigf(p[rr]);
        float sd = sigf(dv / RELAX);
        float tv = (float)((nzmask[b * 1024 + i * 4 + wv] >> (j & 63)) & 1ULL);
        int fg = (int)((~yw[i >> 6] >> (i & 63)) & 1ULL);
        vals[0] += sp * sd * tv;                  // A
        vals[1] += sp * tv;                       // B
        vals[2] += sp * sd;                       // A'
        vals[3] += sp;                            // B'
        vals[4] += fg ? 0.0f : sp;                // C' = sp*(1-fat)
        vals[5] += tv;                            // T
        vals[6] = fminf(vals[6], dv);
        vals[7] = fmaxf(vals[7], dv);
    }
    for (int off = 32; off > 0; off >>= 1) {
        #pragma unroll
        for (int qq = 0; qq < 6; ++qq) vals[qq] += __shfl_down(vals[qq], off, 64);
        vals[6] = fminf(vals[6], __shfl_down(vals[6], off, 64));
        vals[7] = fmaxf(vals[7], __shfl_down(vals[7], off, 64));
    }
    if (lane == 0) {
        #pragma unroll
        for (int qq = 0; qq < 8; ++qq) red[qq][wv] = vals[qq];
    }
    __syncthreads();
    if (tid == 0) {
        float s[8];
        #pragma unroll
        for (int qq = 0; qq < 6; ++qq) s[qq] = red[qq][0] + red[qq][1] + red[qq][2] + red[qq][3];
        s[6] = fminf(fminf(red[6][0], red[6][1]), fminf(red[6][2], red[6][3]));
        s[7] = fmaxf(fmaxf(red[7][0], red[7][1]), fmaxf(red[7][2], red[7][3]));
        part1[blk] = make_float4(s[0], s[1], s[2], s[3]);
        part2[blk] = make_float4(s[4], s[5], s[6], s[7]);
    }
}

// ---------------- tail: fold 32 partials/image, normalize, final scalar -------
__global__ void k_tail(const float4* __restrict__ part1, const float4* __restrict__ part2,
                       float* __restrict__ out) {
    __shared__ float sI[32], sC[32], sA[32];
    int t = threadIdx.x;
    #pragma unroll
    for (int pass = 0; pass < 4; ++pass) {
        int img = pass * 8 + (t >> 5);           // 8 images per pass, 32 lanes each
        int k = t & 31;
        float4 p1 = part1[img * 32 + k];
        float4 p2 = part2[img * 32 + k];
        float vals[8] = {p1.x, p1.y, p1.z, p1.w, p2.x, p2.y, p2.z, p2.w};
        for (int off = 16; off > 0; off >>= 1) {
            #pragma unroll
            for (int qq = 0; qq < 6; ++qq) vals[qq] += __shfl_down(vals[qq], off, 32);
            vals[6] = fminf(vals[6], __shfl_down(vals[6], off, 32));
            vals[7] = fmaxf(vals[7], __shfl_down(vals[7], off, 32));
        }
        if (k == 0) {
            float A = vals[0], Bs = vals[1], Ap = vals[2], Bp = vals[3];
            float Cp = vals[4], T = vals[5], dmn = vals[6], dmx = vals[7];
            float inter, card, any;
            if (dmx > 0.0f) {          // image has foreground
                float smin = sigf(dmn / RELAX);
                float smax = sigf(dmx / RELAX);
                float m = smax - smin;
                float denom = (m > 0.0f) ? m : 1.0f;
                inter = (A - smin * Bs) / denom;   // Σ sp·t·(1-fat) == 0 exactly
                card  = (Ap - smin * Bp) / denom + K_BG * Cp + T;
                any = 1.0f;
            } else {                   // dm = 1 - t ; t == 0 everywhere
                inter = 0.0f;
                card = Bp - Bs + T;
                any = 0.0f;
            }
            sI[img] = inter; sC[img] = card; sA[img] = any;
        }
    }
    __syncthreads();
    if (t == 0) {
        double I = 0.0, C = 0.0;
        int any = 0;
        for (int b = 0; b < BB; ++b) {
            I += (double)sI[b]; C += (double)sC[b];
            any |= (sA[b] > 0.0f);
        }
        double dice = 2.0 * I / fmax(C, (double)EPS_D);
        out[0] = any ? (float)(1.0 - dice) : 0.0f;
    }
}

extern "C" void kernel_launch(void* const* d_in, const int* in_sizes, int n_in,
                              void* d_out, int out_size, void* d_ws, size_t ws_size,
                              hipStream_t stream) {
    const float* preds = (const float*)d_in[0];
    const float* tg    = (const float*)d_in[1];
    float* out = (float*)d_out;

    u64* dmaskT   = (u64*)d_ws;                    // 256 KB
    u64* nzmask   = dmaskT + BB * 1024;            // 256 KB
    u64* cmask    = nzmask + BB * 1024;            // 256 KB
    float4* part1 = (float4*)(cmask + BB * 1024);  // 16 KB, 16B-aligned
    float4* part2 = part1 + BB * 32;               // 16 KB

    hipLaunchKernelGGL(k_maskdil, dim3(BB * 16), dim3(WW), 0, stream, tg, dmaskT, nzmask);
    hipLaunchKernelGGL(k_transp, dim3(BB), dim3(WW), 0, stream, dmaskT, cmask);
    hipLaunchKernelGGL(k_mega, dim3(BB * 32), dim3(WW), 0, stream, preds, cmask, nzmask,
                       part1, part2);
    hipLaunchKernelGGL(k_tail, dim3(1), dim3(256), 0, stream, part1, part2, out);
}

// Round 10
// 93.018 us; speedup vs baseline: 1.0348x; 1.0348x over previous
//
#include <hip/hip_runtime.h>
#include <math.h>

#define BB 32
#define HH 256
#define WW 256
#define HW (HH*WW)
#define K_BG 0.1f
#define RELAX 5.0f
#define EPS_D 1e-7
#define RPB 8              // rows per k_mega block

typedef unsigned long long u64;
typedef unsigned short u16;

__device__ __forceinline__ float sigf(float x) { return 1.0f / (1.0f + expf(-x)); }

__device__ __forceinline__ u64 shflx64(u64 x, int s) {
    return (u64)__shfl_xor((unsigned long long)x, s, 64);
}

// ---------------- binary 5x5 dilation as bit-ops -> row masks ----------------
// dmaskT: dilated mask, WORD-MAJOR  [b][word w][row]   (k_transp's input layout)
// nzmask: raw target mask, row-major [b][row][word]
__global__ void k_maskdil(const float* __restrict__ tg, u64* __restrict__ dmaskT,
                          u64* __restrict__ nzmask) {
    __shared__ u64 nz[20][4];
    __shared__ u64 hd[20][4];
    int blk = blockIdx.x;              // 32 images x 16 bands of 16 rows
    int b = blk >> 4, band = blk & 15;
    int r0 = band * 16;
    int t = threadIdx.x, w = t >> 6;
    const float* img = tg + b * HW;
    float v[20];
    #pragma unroll
    for (int rr = 0; rr < 20; ++rr) {  // all loads issued first: one HBM latency
        int rg = r0 + rr - 2;
        v[rr] = (rg >= 0 && rg < HH) ? img[rg * WW + t] : 0.0f;
    }
    #pragma unroll
    for (int rr = 0; rr < 20; ++rr) {
        u64 bal = __ballot(v[rr] != 0.0f);
        if ((t & 63) == 0) nz[rr][w] = bal;
    }
    __syncthreads();
    if (t < 80) {                      // 20 rows x 4 words: horizontal +-2 dilate
        int rr = t >> 2, k = t & 3;
        u64 m = nz[rr][k];
        u64 ml = (k > 0) ? nz[rr][k - 1] : 0ULL;
        u64 mr = (k < 3) ? nz[rr][k + 1] : 0ULL;
        hd[rr][k] = m | (m << 1) | (m << 2) | (m >> 1) | (m >> 2)
                  | (ml >> 62) | (ml >> 63) | (mr << 62) | (mr << 63);
    }
    if (t < 64) {                      // raw masks for the 16 owned rows
        int rr = t >> 2, k = t & 3;
        nzmask[b * 1024 + (r0 + rr) * 4 + k] = nz[rr + 2][k];
    }
    __syncthreads();
    if (t < 64) {                      // 16 rows x 4 words: vertical +-2 dilate
        int rr = t >> 2, k = t & 3;
        u64 o = hd[rr][k] | hd[rr + 1][k] | hd[rr + 2][k] | hd[rr + 3][k] | hd[rr + 4][k];
        dmaskT[b * 1024 + k * 256 + (r0 + rr)] = o;   // word-major
    }
}

// ---------------- one butterfly bit-transpose per image -> column-major mask --
// cmask[b*1024 + col*4 + g]: bits = rows 64g..64g+63 of column col (dilated mask)
__global__ void k_transp(const u64* __restrict__ dmaskT, u64* __restrict__ cmask) {
    int b = blockIdx.x;
    int tid = threadIdx.x, lane = tid & 63, wv = tid >> 6;
    const u64* base = dmaskT + b * 1024;
    const u64 L32 = 0x00000000FFFFFFFFULL, L16 = 0x0000FFFF0000FFFFULL,
              L8  = 0x00FF00FF00FF00FFULL, L4  = 0x0F0F0F0F0F0F0F0FULL,
              L2  = 0x3333333333333333ULL, L1  = 0x5555555555555555ULL;
    #pragma unroll
    for (int w = 0; w < 4; ++w) {
        u64 x = base[w * 256 + wv * 64 + lane];   // row (64wv+lane), word w
        u64 pp;
        pp = shflx64(x, 32); x = (lane & 32) ? ((x & ~L32) | ((pp & ~L32) >> 32)) : ((x & L32) | ((pp & L32) << 32));
        pp = shflx64(x, 16); x = (lane & 16) ? ((x & ~L16) | ((pp & ~L16) >> 16)) : ((x & L16) | ((pp & L16) << 16));
        pp = shflx64(x,  8); x = (lane &  8) ? ((x & ~L8 ) | ((pp & ~L8 ) >>  8)) : ((x & L8 ) | ((pp & L8 ) <<  8));
        pp = shflx64(x,  4); x = (lane &  4) ? ((x & ~L4 ) | ((pp & ~L4 ) >>  4)) : ((x & L4 ) | ((pp & L4 ) <<  4));
        pp = shflx64(x,  2); x = (lane &  2) ? ((x & ~L2 ) | ((pp & ~L2 ) >>  2)) : ((x & L2 ) | ((pp & L2 ) <<  2));
        pp = shflx64(x,  1); x = (lane &  1) ? ((x & ~L1 ) | ((pp & ~L1 ) >>  1)) : ((x & L1 ) | ((pp & L1 ) <<  1));
        cmask[b * 1024 + (w * 64 + lane) * 4 + wv] = x;   // column-major
    }
}

// ---------------- mega: bit-parallel EDT + dice partials, 8 rows per block ----
// Vertical distance = clz/ctz over the precomputed column mask. Horizontal
// min-plus: branchless r=1..8 prefix (independent LDS reads, no dep chain),
// early-exit tail from r=9 for the rare far pixels. f32 arithmetic identical
// to the reference separable EDT (all values exact; single-rounded adds).
__global__ __launch_bounds__(256) void k_mega(const float* __restrict__ preds,
                                              const u64* __restrict__ cmask,
                                              const u64* __restrict__ nzmask,
                                              float4* __restrict__ part1,
                                              float4* __restrict__ part2) {
    __shared__ u16 gS[RPB][WW];
    __shared__ float red[8][4];
    int blk = blockIdx.x;              // b*32 + q ; rows 8q..8q+7
    int b = blk >> 5, q = blk & 31;
    int i0 = q * RPB;
    int tid = threadIdx.x;
    int lane = tid & 63, wv = tid >> 6;
    int j = tid;                       // this thread's column

    float p[RPB];
    #pragma unroll
    for (int rr = 0; rr < RPB; ++rr)
        p[rr] = preds[(b * HH + i0 + rr) * WW + j];
    u64 nzw[RPB];
    #pragma unroll
    for (int rr = 0; rr < RPB; ++rr)
        nzw[rr] = nzmask[b * 1024 + (i0 + rr) * 4 + wv];

    u64 yw[4];                         // set bit = zero pixel, column j
    {
        const u64* cm = cmask + b * 1024 + j * 4;
        #pragma unroll
        for (int g = 0; g < 4; ++g) yw[g] = ~cm[g];
    }

    // ---- branchless vertical distance for RPB pixels (same column) ----
    int g0v[RPB], fgv[RPB];
    #pragma unroll
    for (int rr = 0; rr < RPB; ++rr) {
        int i = i0 + rr;
        int iw = i >> 6, ib = i & 63;
        u64 lowm  = (2ULL << ib) - 1ULL;          // bits 0..ib (ib=63 -> ~0)
        u64 highm = ~((1ULL << ib) - 1ULL);       // bits ib..63
        int pu = -1, pd = -1;
        #pragma unroll
        for (int w = 0; w < 4; ++w) {             // ascending: highest nonzero word wins
            u64 m = (w < iw) ? ~0ULL : ((w == iw) ? lowm : 0ULL);
            u64 z = yw[w] & m;
            int cand = (w << 6) + 63 - __clzll(z);
            pu = z ? cand : pu;
        }
        #pragma unroll
        for (int w = 3; w >= 0; --w) {            // descending: lowest nonzero word wins
            u64 m = (w > iw) ? ~0ULL : ((w == iw) ? highm : 0ULL);
            u64 z = yw[w] & m;
            int cand = (w << 6) + (__ffsll((unsigned long long)z) - 1);
            pd = z ? cand : pd;
        }
        int up = (pu >= 0) ? (i - pu) : 10000;
        int dn = (pd >= 0) ? (pd - i) : 10000;
        int g0 = min(min(up, dn), 10000);
        g0v[rr] = g0;
        fgv[rr] = (int)((~yw[iw] >> ib) & 1ULL);
        gS[rr][j] = (u16)g0;
    }
    __syncthreads();

    // ---- min-plus walk + dice partials ----
    float vals[8];
    #pragma unroll
    for (int qq = 0; qq < 6; ++qq) vals[qq] = 0.0f;
    vals[6] = 1e30f; vals[7] = 0.0f;
    #pragma unroll
    for (int rr = 0; rr < RPB; ++rr) {
        float gv = (float)g0v[rr];
        float best = gv * gv;
        #pragma unroll
        for (int r = 1; r <= 8; ++r) {            // branchless prefix: no dep chain
            float rf = (float)(r * r);
            int jl = j - r, jr = j + r;
            float vl = (jl >= 0) ? (float)gS[rr][jl] : 1e4f;
            float vr = (jr < WW) ? (float)gS[rr][jr] : 1e4f;
            best = fminf(best, fminf(fmaf(vl, vl, rf), fmaf(vr, vr, rf)));
        }
        for (int r = 9; r < WW; ++r) {            // rare far tail
            float rf = (float)(r * r);
            if (rf >= best) break;
            int jl = j - r, jr = j + r;
            if (jl >= 0) { float v = (float)gS[rr][jl]; best = fminf(best, fmaf(v, v, rf)); }
            if (jr < WW) { float v = (float)gS[rr][jr]; best = fminf(best, fmaf(v, v, rf)); }
        }
        float dv = sqrtf(best);
        float sp = sigf(p[rr]);
        float sd = sigf(dv / RELAX);
        float tv = (float)((nzw[rr] >> (j & 63)) & 1ULL);
        vals[0] += sp * sd * tv;                  // A
        vals[1] += sp * tv;                       // B
        vals[2] += sp * sd;                       // A'
        vals[3] += sp;                            // B'
        vals[4] += fgv[rr] ? 0.0f : sp;           // C' = sp*(1-fat)
        vals[5] += tv;                            // T
        vals[6] = fminf(vals[6], dv);
        vals[7] = fmaxf(vals[7], dv);
    }
    for (int off = 32; off > 0; off >>= 1) {
        #pragma unroll
        for (int qq = 0; qq < 6; ++qq) vals[qq] += __shfl_down(vals[qq], off, 64);
        vals[6] = fminf(vals[6], __shfl_down(vals[6], off, 64));
        vals[7] = fmaxf(vals[7], __shfl_down(vals[7], off, 64));
    }
    if (lane == 0) {
        #pragma unroll
        for (int qq = 0; qq < 8; ++qq) red[qq][wv] = vals[qq];
    }
    __syncthreads();
    if (tid == 0) {
        float s[8];
        #pragma unroll
        for (int qq = 0; qq < 6; ++qq) s[qq] = red[qq][0] + red[qq][1] + red[qq][2] + red[qq][3];
        s[6] = fminf(fminf(red[6][0], red[6][1]), fminf(red[6][2], red[6][3]));
        s[7] = fmaxf(fmaxf(red[7][0], red[7][1]), fmaxf(red[7][2], red[7][3]));
        part1[blk] = make_float4(s[0], s[1], s[2], s[3]);
        part2[blk] = make_float4(s[4], s[5], s[6], s[7]);
    }
}

// ---------------- tail: fold 32 partials/image, normalize, final scalar -------
__global__ void k_tail(const float4* __restrict__ part1, const float4* __restrict__ part2,
                       float* __restrict__ out) {
    __shared__ float sI[32], sC[32], sA[32];
    int t = threadIdx.x;
    #pragma unroll
    for (int pass = 0; pass < 4; ++pass) {
        int img = pass * 8 + (t >> 5);           // 8 images per pass, 32 lanes each
        int k = t & 31;
        float4 p1 = part1[img * 32 + k];
        float4 p2 = part2[img * 32 + k];
        float vals[8] = {p1.x, p1.y, p1.z, p1.w, p2.x, p2.y, p2.z, p2.w};
        for (int off = 16; off > 0; off >>= 1) {
            #pragma unroll
            for (int qq = 0; qq < 6; ++qq) vals[qq] += __shfl_down(vals[qq], off, 32);
            vals[6] = fminf(vals[6], __shfl_down(vals[6], off, 32));
            vals[7] = fmaxf(vals[7], __shfl_down(vals[7], off, 32));
        }
        if (k == 0) {
            float A = vals[0], Bs = vals[1], Ap = vals[2], Bp = vals[3];
            float Cp = vals[4], T = vals[5], dmn = vals[6], dmx = vals[7];
            float inter, card, any;
            if (dmx > 0.0f) {          // image has foreground
                float smin = sigf(dmn / RELAX);
                float smax = sigf(dmx / RELAX);
                float m = smax - smin;
                float denom = (m > 0.0f) ? m : 1.0f;
                inter = (A - smin * Bs) / denom;   // Σ sp·t·(1-fat) == 0 exactly
                card  = (Ap - smin * Bp) / denom + K_BG * Cp + T;
                any = 1.0f;
            } else {                   // dm = 1 - t ; t == 0 everywhere
                inter = 0.0f;
                card = Bp - Bs + T;
                any = 0.0f;
            }
            sI[img] = inter; sC[img] = card; sA[img] = any;
        }
    }
    __syncthreads();
    if (t == 0) {
        double I = 0.0, C = 0.0;
        int any = 0;
        for (int b = 0; b < BB; ++b) {
            I += (double)sI[b]; C += (double)sC[b];
            any |= (sA[b] > 0.0f);
        }
        double dice = 2.0 * I / fmax(C, (double)EPS_D);
        out[0] = any ? (float)(1.0 - dice) : 0.0f;
    }
}

extern "C" void kernel_launch(void* const* d_in, const int* in_sizes, int n_in,
                              void* d_out, int out_size, void* d_ws, size_t ws_size,
                              hipStream_t stream) {
    const float* preds = (const float*)d_in[0];
    const float* tg    = (const float*)d_in[1];
    float* out = (float*)d_out;

    u64* dmaskT   = (u64*)d_ws;                    // 256 KB
    u64* nzmask   = dmaskT + BB * 1024;            // 256 KB
    u64* cmask    = nzmask + BB * 1024;            // 256 KB
    float4* part1 = (float4*)(cmask + BB * 1024);  // 16 KB, 16B-aligned
    float4* part2 = part1 + BB * 32;               // 16 KB

    hipLaunchKernelGGL(k_maskdil, dim3(BB * 16), dim3(WW), 0, stream, tg, dmaskT, nzmask);
    hipLaunchKernelGGL(k_transp, dim3(BB), dim3(WW), 0, stream, dmaskT, cmask);
    hipLaunchKernelGGL(k_mega, dim3(BB * 32), dim3(WW), 0, stream, preds, cmask, nzmask,
                       part1, part2);
    hipLaunchKernelGGL(k_tail, dim3(1), dim3(256), 0, stream, part1, part2, out);
}

// Round 11
// 90.819 us; speedup vs baseline: 1.0598x; 1.0242x over previous
//
#include <hip/hip_runtime.h>
#include <math.h>

#define BB 32
#define HH 256
#define WW 256
#define HW (HH*WW)
#define K_BG 0.1f
#define RELAX 5.0f
#define EPS_D 1e-7
#define RPB 8              // rows per k_mega block

typedef unsigned long long u64;
typedef unsigned short u16;

__device__ __forceinline__ float sigf(float x) { return 1.0f / (1.0f + expf(-x)); }

__device__ __forceinline__ u64 shflx64(u64 x, int s) {
    return (u64)__shfl_xor((unsigned long long)x, s, 64);
}

// ---------------- binary 5x5 dilation as bit-ops -> row masks ----------------
// dmaskT: dilated mask, WORD-MAJOR  [b][word w][row]   (k_mega's transpose input)
// nzmask: raw target mask, row-major [b][row][word]
__global__ void k_maskdil(const float* __restrict__ tg, u64* __restrict__ dmaskT,
                          u64* __restrict__ nzmask) {
    __shared__ u64 nz[20][4];
    __shared__ u64 hd[20][4];
    int blk = blockIdx.x;              // 32 images x 16 bands of 16 rows
    int b = blk >> 4, band = blk & 15;
    int r0 = band * 16;
    int t = threadIdx.x, w = t >> 6;
    const float* img = tg + b * HW;
    float v[20];
    #pragma unroll
    for (int rr = 0; rr < 20; ++rr) {  // all loads issued first: one HBM latency
        int rg = r0 + rr - 2;
        v[rr] = (rg >= 0 && rg < HH) ? img[rg * WW + t] : 0.0f;
    }
    #pragma unroll
    for (int rr = 0; rr < 20; ++rr) {
        u64 bal = __ballot(v[rr] != 0.0f);
        if ((t & 63) == 0) nz[rr][w] = bal;
    }
    __syncthreads();
    if (t < 80) {                      // 20 rows x 4 words: horizontal +-2 dilate
        int rr = t >> 2, k = t & 3;
        u64 m = nz[rr][k];
        u64 ml = (k > 0) ? nz[rr][k - 1] : 0ULL;
        u64 mr = (k < 3) ? nz[rr][k + 1] : 0ULL;
        hd[rr][k] = m | (m << 1) | (m << 2) | (m >> 1) | (m >> 2)
                  | (ml >> 62) | (ml >> 63) | (mr << 62) | (mr << 63);
    }
    if (t < 64) {                      // raw masks for the 16 owned rows
        int rr = t >> 2, k = t & 3;
        nzmask[b * 1024 + (r0 + rr) * 4 + k] = nz[rr + 2][k];
    }
    __syncthreads();
    if (t < 64) {                      // 16 rows x 4 words: vertical +-2 dilate
        int rr = t >> 2, k = t & 3;
        u64 o = hd[rr][k] | hd[rr + 1][k] | hd[rr + 2][k] | hd[rr + 3][k] | hd[rr + 4][k];
        dmaskT[b * 1024 + k * 256 + (r0 + rr)] = o;   // word-major
    }
}

// ---------------- mega: transpose + bit-parallel EDT + dice partials ----------
// Per-block butterfly bit-transpose (measured free in R8) -> per-column 256-bit
// masks in LDS. Vertical distance = clz/ctz. Horizontal min-plus: branchless
// r=1..8 prefix, then 8-wide branchless CHUNKS with one break test per chunk
// (kills the dependent per-iteration LDS latency chain). All f32 arithmetic
// identical to the reference separable EDT (extra candidates are exact and
// cannot change the min; 1e4 substitution == the reference INF sentinel).
__global__ __launch_bounds__(256) void k_mega(const float* __restrict__ preds,
                                              const u64* __restrict__ dmaskT,
                                              const u64* __restrict__ nzmask,
                                              float4* __restrict__ part1,
                                              float4* __restrict__ part2) {
    __shared__ u64 colT[4 * 256];      // [rowgroup g][col] : bits = rows 64g..64g+63
    __shared__ u16 gS[RPB][WW];
    __shared__ float red[8][4];
    int blk = blockIdx.x;              // b*32 + q ; rows 8q..8q+7
    int b = blk >> 5, q = blk & 31;
    int i0 = q * RPB;
    int tid = threadIdx.x;
    int lane = tid & 63, wv = tid >> 6;
    int j = tid;                       // this thread's column

    float p[RPB];                      // issue HBM loads first; consumed much later
    #pragma unroll
    for (int rr = 0; rr < RPB; ++rr)
        p[rr] = preds[(b * HH + i0 + rr) * WW + j];
    u64 nzw[RPB];
    #pragma unroll
    for (int rr = 0; rr < RPB; ++rr)
        nzw[rr] = nzmask[b * 1024 + (i0 + rr) * 4 + wv];

    // ---- register bit-transpose: wave wv owns row-group wv ----
    const u64* base = dmaskT + b * 1024;
    const u64 L32 = 0x00000000FFFFFFFFULL, L16 = 0x0000FFFF0000FFFFULL,
              L8  = 0x00FF00FF00FF00FFULL, L4  = 0x0F0F0F0F0F0F0F0FULL,
              L2  = 0x3333333333333333ULL, L1  = 0x5555555555555555ULL;
    #pragma unroll
    for (int w = 0; w < 4; ++w) {
        u64 x = base[w * 256 + wv * 64 + lane];   // row (64wv+lane), word w
        u64 pp;
        pp = shflx64(x, 32); x = (lane & 32) ? ((x & ~L32) | ((pp & ~L32) >> 32)) : ((x & L32) | ((pp & L32) << 32));
        pp = shflx64(x, 16); x = (lane & 16) ? ((x & ~L16) | ((pp & ~L16) >> 16)) : ((x & L16) | ((pp & L16) << 16));
        pp = shflx64(x,  8); x = (lane &  8) ? ((x & ~L8 ) | ((pp & ~L8 ) >>  8)) : ((x & L8 ) | ((pp & L8 ) <<  8));
        pp = shflx64(x,  4); x = (lane &  4) ? ((x & ~L4 ) | ((pp & ~L4 ) >>  4)) : ((x & L4 ) | ((pp & L4 ) <<  4));
        pp = shflx64(x,  2); x = (lane &  2) ? ((x & ~L2 ) | ((pp & ~L2 ) >>  2)) : ((x & L2 ) | ((pp & L2 ) <<  2));
        pp = shflx64(x,  1); x = (lane &  1) ? ((x & ~L1 ) | ((pp & ~L1 ) >>  1)) : ((x & L1 ) | ((pp & L1 ) <<  1));
        colT[wv * 256 + w * 64 + lane] = x;       // column (64w+lane), row-group wv
    }
    __syncthreads();

    u64 yw[4];                         // set bit = zero pixel, column j
    #pragma unroll
    for (int g = 0; g < 4; ++g) yw[g] = ~colT[g * 256 + j];

    // ---- branchless vertical distance for RPB pixels (same column) ----
    int g0v[RPB], fgv[RPB];
    #pragma unroll
    for (int rr = 0; rr < RPB; ++rr) {
        int i = i0 + rr;
        int iw = i >> 6, ib = i & 63;
        u64 lowm  = (2ULL << ib) - 1ULL;          // bits 0..ib (ib=63 -> ~0)
        u64 highm = ~((1ULL << ib) - 1ULL);       // bits ib..63
        int pu = -1, pd = -1;
        #pragma unroll
        for (int w = 0; w < 4; ++w) {             // ascending: highest nonzero word wins
            u64 m = (w < iw) ? ~0ULL : ((w == iw) ? lowm : 0ULL);
            u64 z = yw[w] & m;
            int cand = (w << 6) + 63 - __clzll(z);
            pu = z ? cand : pu;
        }
        #pragma unroll
        for (int w = 3; w >= 0; --w) {            // descending: lowest nonzero word wins
            u64 m = (w > iw) ? ~0ULL : ((w == iw) ? highm : 0ULL);
            u64 z = yw[w] & m;
            int cand = (w << 6) + (__ffsll((unsigned long long)z) - 1);
            pd = z ? cand : pd;
        }
        int up = (pu >= 0) ? (i - pu) : 10000;
        int dn = (pd >= 0) ? (pd - i) : 10000;
        int g0 = min(min(up, dn), 10000);
        g0v[rr] = g0;
        fgv[rr] = (int)((~yw[iw] >> ib) & 1ULL);
        gS[rr][j] = (u16)g0;
    }
    __syncthreads();

    // ---- min-plus walk (prefix + chunked tail) + dice partials ----
    float vals[8];
    #pragma unroll
    for (int qq = 0; qq < 6; ++qq) vals[qq] = 0.0f;
    vals[6] = 1e30f; vals[7] = 0.0f;
    #pragma unroll
    for (int rr = 0; rr < RPB; ++rr) {
        float gv = (float)g0v[rr];
        float best = gv * gv;
        #pragma unroll
        for (int r = 1; r <= 8; ++r) {            // branchless prefix
            float rf = (float)(r * r);
            int jl = j - r, jr = j + r;
            float vl = (jl >= 0) ? (float)gS[rr][jl] : 1e4f;
            float vr = (jr < WW) ? (float)gS[rr][jr] : 1e4f;
            best = fminf(best, fminf(fmaf(vl, vl, rf), fmaf(vr, vr, rf)));
        }
        for (int rc = 9; rc < WW + 8; rc += 8) {  // branchless 8-chunks, 1 test/chunk
            if ((float)(rc * rc) >= best) break;
            #pragma unroll
            for (int dr = 0; dr < 8; ++dr) {
                int r = rc + dr;
                float rf = (float)(r * r);
                int jl = j - r, jr = j + r;
                float vl = (jl >= 0) ? (float)gS[rr][jl] : 1e4f;
                float vr = (jr < WW) ? (float)gS[rr][jr] : 1e4f;
                best = fminf(best, fminf(fmaf(vl, vl, rf), fmaf(vr, vr, rf)));
            }
        }
        float dv = sqrtf(best);
        float sp = sigf(p[rr]);
        float sd = sigf(dv / RELAX);
        float tv = (float)((nzw[rr] >> (j & 63)) & 1ULL);
        vals[0] += sp * sd * tv;                  // A
        vals[1] += sp * tv;                       // B
        vals[2] += sp * sd;                       // A'
        vals[3] += sp;                            // B'
        vals[4] += fgv[rr] ? 0.0f : sp;           // C' = sp*(1-fat)
        vals[5] += tv;                            // T
        vals[6] = fminf(vals[6], dv);
        vals[7] = fmaxf(vals[7], dv);
    }
    for (int off = 32; off > 0; off >>= 1) {
        #pragma unroll
        for (int qq = 0; qq < 6; ++qq) vals[qq] += __shfl_down(vals[qq], off, 64);
        vals[6] = fminf(vals[6], __shfl_down(vals[6], off, 64));
        vals[7] = fmaxf(vals[7], __shfl_down(vals[7], off, 64));
    }
    if (lane == 0) {
        #pragma unroll
        for (int qq = 0; qq < 8; ++qq) red[qq][wv] = vals[qq];
    }
    __syncthreads();
    if (tid == 0) {
        float s[8];
        #pragma unroll
        for (int qq = 0; qq < 6; ++qq) s[qq] = red[qq][0] + red[qq][1] + red[qq][2] + red[qq][3];
        s[6] = fminf(fminf(red[6][0], red[6][1]), fminf(red[6][2], red[6][3]));
        s[7] = fmaxf(fmaxf(red[7][0], red[7][1]), fmaxf(red[7][2], red[7][3]));
        part1[blk] = make_float4(s[0], s[1], s[2], s[3]);
        part2[blk] = make_float4(s[4], s[5], s[6], s[7]);
    }
}

// ---------------- tail: fold 32 partials/image, normalize, final scalar -------
__global__ void k_tail(const float4* __restrict__ part1, const float4* __restrict__ part2,
                       float* __restrict__ out) {
    __shared__ float sI[32], sC[32], sA[32];
    int t = threadIdx.x;
    #pragma unroll
    for (int pass = 0; pass < 4; ++pass) {
        int img = pass * 8 + (t >> 5);           // 8 images per pass, 32 lanes each
        int k = t & 31;
        float4 p1 = part1[img * 32 + k];
        float4 p2 = part2[img * 32 + k];
        float vals[8] = {p1.x, p1.y, p1.z, p1.w, p2.x, p2.y, p2.z, p2.w};
        for (int off = 16; off > 0; off >>= 1) {
            #pragma unroll
            for (int qq = 0; qq < 6; ++qq) vals[qq] += __shfl_down(vals[qq], off, 32);
            vals[6] = fminf(vals[6], __shfl_down(vals[6], off, 32));
            vals[7] = fmaxf(vals[7], __shfl_down(vals[7], off, 32));
        }
        if (k == 0) {
            float A = vals[0], Bs = vals[1], Ap = vals[2], Bp = vals[3];
            float Cp = vals[4], T = vals[5], dmn = vals[6], dmx = vals[7];
            float inter, card, any;
            if (dmx > 0.0f) {          // image has foreground
                float smin = sigf(dmn / RELAX);
                float smax = sigf(dmx / RELAX);
                float m = smax - smin;
                float denom = (m > 0.0f) ? m : 1.0f;
                inter = (A - smin * Bs) / denom;   // Σ sp·t·(1-fat) == 0 exactly
                card  = (Ap - smin * Bp) / denom + K_BG * Cp + T;
                any = 1.0f;
            } else {                   // dm = 1 - t ; t == 0 everywhere
                inter = 0.0f;
                card = Bp - Bs + T;
                any = 0.0f;
            }
            sI[img] = inter; sC[img] = card; sA[img] = any;
        }
    }
    __syncthreads();
    if (t == 0) {
        double I = 0.0, C = 0.0;
        int any = 0;
        for (int b = 0; b < BB; ++b) {
            I += (double)sI[b]; C += (double)sC[b];
            any |= (sA[b] > 0.0f);
        }
        double dice = 2.0 * I / fmax(C, (double)EPS_D);
        out[0] = any ? (float)(1.0 - dice) : 0.0f;
    }
}

extern "C" void kernel_launch(void* const* d_in, const int* in_sizes, int n_in,
                              void* d_out, int out_size, void* d_ws, size_t ws_size,
                              hipStream_t stream) {
    const float* preds = (const float*)d_in[0];
    const float* tg    = (const float*)d_in[1];
    float* out = (float*)d_out;

    u64* dmaskT   = (u64*)d_ws;                    // 256 KB
    u64* nzmask   = dmaskT + BB * 1024;            // 256 KB
    float4* part1 = (float4*)(nzmask + BB * 1024); // 16 KB, 16B-aligned
    float4* part2 = part1 + BB * 32;               // 16 KB

    hipLaunchKernelGGL(k_maskdil, dim3(BB * 16), dim3(WW), 0, stream, tg, dmaskT, nzmask);
    hipLaunchKernelGGL(k_mega, dim3(BB * 32), dim3(WW), 0, stream, preds, dmaskT, nzmask,
                       part1, part2);
    hipLaunchKernelGGL(k_tail, dim3(1), dim3(256), 0, stream, part1, part2, out);
}